// Round 5
// baseline (440.322 us; speedup 1.0000x reference)
//
#include <hip/hip_runtime.h>
#include <cstdint>
#include <cstddef>

#define FD 128
#define CO 64
#define NB 256     // partition blocks
#define NBINS 256  // buckets (node>>8); requires N <= 65536

typedef short bf16x8 __attribute__((ext_vector_type(8)));
typedef float f32x4 __attribute__((ext_vector_type(4)));
typedef unsigned int uint32;

__device__ __forceinline__ unsigned short f2bf(float f) {
  unsigned u = __float_as_uint(f);
  unsigned r = u + 0x7fffu + ((u >> 16) & 1u);
  return (unsigned short)(r >> 16);
}
__device__ __forceinline__ float bf2f(unsigned short b) {
  return __uint_as_float((unsigned)b << 16);
}

// ---------------- CSR build: scan-based counting sort (no global atomics) ----------------

// per-block 256-bin LDS histograms of dst>>8 and src>>8
__global__ __launch_bounds__(256) void k_hist(const int* __restrict__ src,
                                              const int* __restrict__ dst,
                                              int* __restrict__ histD,
                                              int* __restrict__ histS,
                                              int E, int chunk) {
  __shared__ int hd[NBINS], hs[NBINS];
  int tid = threadIdx.x, blk = blockIdx.x;
  hd[tid] = 0;
  hs[tid] = 0;
  __syncthreads();
  int beg = blk * chunk;
  int end = min(E, beg + chunk);
  for (int e = beg + tid; e < end; e += 256) {
    atomicAdd(&hd[dst[e] >> 8], 1);
    atomicAdd(&hs[src[e] >> 8], 1);
  }
  __syncthreads();
  histD[tid * NB + blk] = hd[tid];  // bin-major layout
  histS[tid * NB + blk] = hs[tid];
}

// in-place exclusive scan of one L-length array (L divisible by 1024), 1 block
__device__ void scan_inplace(int* a, int L, int* part) {
  int tid = threadIdx.x;
  int chunk = L >> 10;
  int base = tid * chunk;
  int s = 0;
  for (int i = 0; i < chunk; i++) s += a[base + i];
  part[tid] = s;
  __syncthreads();
  for (int o = 1; o < 1024; o <<= 1) {
    int t = (tid >= o) ? part[tid - o] : 0;
    __syncthreads();
    part[tid] += t;
    __syncthreads();
  }
  int run = (tid == 0) ? 0 : part[tid - 1];
  for (int i = 0; i < chunk; i++) {
    int v = a[base + i];
    a[base + i] = run;
    run += v;
  }
}

__global__ __launch_bounds__(1024) void k_scan2(int* __restrict__ a,
                                                int* __restrict__ b, int L) {
  __shared__ int part[1024];
  scan_inplace(a, L, part);
  __syncthreads();
  scan_inplace(b, L, part);
}

// partition edges into dst-buckets (dstB,srcB) and src ids into src-buckets (srcS)
__global__ __launch_bounds__(256) void k_scatter(const int* __restrict__ src,
                                                 const int* __restrict__ dst,
                                                 const int* __restrict__ offD,
                                                 const int* __restrict__ offS,
                                                 int* __restrict__ dstB,
                                                 int* __restrict__ srcB,
                                                 int* __restrict__ srcS,
                                                 int E, int chunk) {
  __shared__ int runD[NBINS], runS[NBINS];
  int tid = threadIdx.x, blk = blockIdx.x;
  runD[tid] = offD[tid * NB + blk];
  runS[tid] = offS[tid * NB + blk];
  __syncthreads();
  int beg = blk * chunk;
  int end = min(E, beg + chunk);
  for (int e = beg + tid; e < end; e += 256) {
    int s = src[e], d = dst[e];
    int p = atomicAdd(&runD[d >> 8], 1);
    dstB[p] = d;
    srcB[p] = s;
    int q = atomicAdd(&runS[s >> 8], 1);
    srcS[q] = s;
  }
}

// per-bucket: count deg_in -> row_ptr, d_dst; scatter srcB into final CSR esrc
__global__ __launch_bounds__(256) void k_bucket_dst(const int* __restrict__ dstB,
                                                    const int* __restrict__ srcB,
                                                    const int* __restrict__ offD,
                                                    int* __restrict__ esrc,
                                                    int* __restrict__ row_ptr,
                                                    float* __restrict__ d_dst,
                                                    int N, int E) {
  __shared__ int cnt[NBINS], run[NBINS];
  int tid = threadIdx.x, bin = blockIdx.x;
  int start = offD[bin * NB];
  int end = (bin == NBINS - 1) ? E : offD[(bin + 1) * NB];
  cnt[tid] = 0;
  __syncthreads();
  for (int p = start + tid; p < end; p += 256) atomicAdd(&cnt[dstB[p] & 255], 1);
  __syncthreads();
  int v = cnt[tid];
  run[tid] = v;
  __syncthreads();
  for (int o = 1; o < 256; o <<= 1) {
    int t = (tid >= o) ? run[tid - o] : 0;
    __syncthreads();
    run[tid] += t;
    __syncthreads();
  }
  int excl = run[tid] - v;
  int node = bin * 256 + tid;
  if (node < N) {
    row_ptr[node] = start + excl;
    d_dst[node] = rsqrtf((float)(v > 0 ? v : 1));
  }
  __syncthreads();
  run[tid] = start + excl;  // reuse as scatter cursor
  __syncthreads();
  for (int p = start + tid; p < end; p += 256) {
    int d = dstB[p];
    int slot = atomicAdd(&run[d & 255], 1);
    esrc[slot] = srcB[p];
  }
  if (bin == 0 && tid == 0) row_ptr[N] = E;
}

// per-bucket: count deg_out -> d_src
__global__ __launch_bounds__(256) void k_bucket_src(const int* __restrict__ srcS,
                                                    const int* __restrict__ offS,
                                                    float* __restrict__ d_src,
                                                    int N, int E) {
  __shared__ int cnt[NBINS];
  int tid = threadIdx.x, bin = blockIdx.x;
  int start = offS[bin * NB];
  int end = (bin == NBINS - 1) ? E : offS[(bin + 1) * NB];
  cnt[tid] = 0;
  __syncthreads();
  for (int p = start + tid; p < end; p += 256) atomicAdd(&cnt[srcS[p] & 255], 1);
  __syncthreads();
  int node = bin * 256 + tid;
  if (node < N) {
    int v = cnt[tid];
    d_src[node] = rsqrtf((float)(v > 0 ? v : 1));
  }
}

// ---------------- MFMA GEMM ----------------
// A: bf16 [N][128] (ABF16) or fp32 (rounded to bf16 at staging).
// W: fp32, split hi/lo bf16 (weight error ~2^-18).
// epilogue: v = acc * (SCALE ? rscale[row] : 1) + (BIAS ? bias[col] : 0).

template <int NCW, bool ABF16, bool SCALE, bool BIAS, bool OUTBF16>
__global__ __launch_bounds__(256) void k_gemm(const void* __restrict__ Av,
                                              const float* __restrict__ W,
                                              const float* __restrict__ bias,
                                              const float* __restrict__ rscale,
                                              void* __restrict__ outv, int N) {
  extern __shared__ char smem[];
  bf16x8* Ah = (bf16x8*)smem;   // [16 kc][64 row] 16B slots = 16KB
  bf16x8* Wh = Ah + 1024;       // [16 kc][64 col] 16KB
  bf16x8* Wl = Wh + 1024;       // 16KB
  int tid = threadIdx.x;
  int rowBase = blockIdx.x * 64;
  int colBase = blockIdx.y * 64;

#pragma unroll
  for (int t = 0; t < 4; t++) {
    int p = t * 256 + tid;
    int kc = p >> 6, col = p & 63;
    bf16x8 h, l;
#pragma unroll
    for (int j = 0; j < 8; j++) {
      float v = W[(size_t)(kc * 8 + j) * NCW + colBase + col];
      unsigned short hb = f2bf(v);
      h[j] = (short)hb;
      l[j] = (short)f2bf(v - bf2f(hb));
    }
    Wh[kc * 64 + col] = h;
    Wl[kc * 64 + col] = l;
  }
#pragma unroll
  for (int t = 0; t < 4; t++) {
    int p = t * 256 + tid;
    int kc = p >> 6, row = p & 63;
    int gr = rowBase + row;
    bf16x8 h = {0, 0, 0, 0, 0, 0, 0, 0};
    if (gr < N) {
      if (ABF16) {
        h = *(const bf16x8*)((const unsigned short*)Av + (size_t)gr * FD + kc * 8);
      } else {
        const float4* A4 = (const float4*)((const float*)Av + (size_t)gr * FD + kc * 8);
        float4 u = A4[0];
        float4 v = A4[1];
        float vals[8] = {u.x, u.y, u.z, u.w, v.x, v.y, v.z, v.w};
#pragma unroll
        for (int j = 0; j < 8; j++) h[j] = (short)f2bf(vals[j]);
      }
    }
    Ah[kc * 64 + row] = h;
  }
  __syncthreads();

  int wv = tid >> 6, lane = tid & 63;
  int wr = (wv >> 1) * 32, wc = (wv & 1) * 32;
  int lhi = lane >> 4, llo = lane & 15;
  f32x4 acc[2][2] = {};

#pragma unroll
  for (int ks = 0; ks < 4; ks++) {
    int kcg = ks * 4 + lhi;
    int abase = kcg * 64 + wr + llo;
    int bbase = kcg * 64 + wc + llo;
    bf16x8 a0 = Ah[abase];
    bf16x8 a1 = Ah[abase + 16];
    bf16x8 bh0 = Wh[bbase];
    bf16x8 bh1 = Wh[bbase + 16];
    bf16x8 bl0 = Wl[bbase];
    bf16x8 bl1 = Wl[bbase + 16];
    acc[0][0] = __builtin_amdgcn_mfma_f32_16x16x32_bf16(a0, bh0, acc[0][0], 0, 0, 0);
    acc[0][1] = __builtin_amdgcn_mfma_f32_16x16x32_bf16(a0, bh1, acc[0][1], 0, 0, 0);
    acc[1][0] = __builtin_amdgcn_mfma_f32_16x16x32_bf16(a1, bh0, acc[1][0], 0, 0, 0);
    acc[1][1] = __builtin_amdgcn_mfma_f32_16x16x32_bf16(a1, bh1, acc[1][1], 0, 0, 0);
    acc[0][0] = __builtin_amdgcn_mfma_f32_16x16x32_bf16(a0, bl0, acc[0][0], 0, 0, 0);
    acc[0][1] = __builtin_amdgcn_mfma_f32_16x16x32_bf16(a0, bl1, acc[0][1], 0, 0, 0);
    acc[1][0] = __builtin_amdgcn_mfma_f32_16x16x32_bf16(a1, bl0, acc[1][0], 0, 0, 0);
    acc[1][1] = __builtin_amdgcn_mfma_f32_16x16x32_bf16(a1, bl1, acc[1][1], 0, 0, 0);
  }

  float bv0 = 0.f, bv1 = 0.f;
  if (BIAS) {
    bv0 = bias[colBase + wc + llo];
    bv1 = bias[colBase + wc + 16 + llo];
  }
  float rs[2][4];
  if (SCALE) {
#pragma unroll
    for (int mf = 0; mf < 2; mf++)
#pragma unroll
      for (int r = 0; r < 4; r++) {
        int row = rowBase + wr + mf * 16 + lhi * 4 + r;
        rs[mf][r] = (row < N) ? rscale[row] : 0.f;
      }
  }
#pragma unroll
  for (int mf = 0; mf < 2; mf++) {
#pragma unroll
    for (int nf = 0; nf < 2; nf++) {
      float bv = nf ? bv1 : bv0;
      int col = colBase + wc + nf * 16 + llo;
#pragma unroll
      for (int r = 0; r < 4; r++) {
        int row = rowBase + wr + mf * 16 + lhi * 4 + r;
        if (row < N) {
          float v = acc[mf][nf][r];
          if (SCALE) v *= rs[mf][r];
          v += bv;
          if (OUTBF16)
            ((unsigned short*)outv)[(size_t)row * NCW + col] = f2bf(v);
          else
            ((float*)outv)[(size_t)row * NCW + col] = v;
        }
      }
    }
  }
}

// ---------------- Aggregation (bf16 rows) ----------------

template <bool RELU, bool RES>
__global__ __launch_bounds__(256) void k_agg(const unsigned short* __restrict__ h,
                                             const int* __restrict__ row_ptr,
                                             const int* __restrict__ esrc,
                                             const float* __restrict__ d_dst,
                                             const float* __restrict__ bias,
                                             const unsigned short* __restrict__ res,
                                             unsigned short* __restrict__ out, int N) {
  int node = blockIdx.x * 4 + (threadIdx.x >> 6);
  int lane = threadIdx.x & 63;
  if (node >= N) return;
  int beg = row_ptr[node], end = row_ptr[node + 1];
  const uint32* h4 = (const uint32*)h;
  float ax = 0.f, ay = 0.f;
  int e = beg;
  for (; e + 4 <= end; e += 4) {
    int s0 = esrc[e + 0];
    int s1 = esrc[e + 1];
    int s2 = esrc[e + 2];
    int s3 = esrc[e + 3];
    uint32 v0 = h4[(size_t)s0 * 64 + lane];
    uint32 v1 = h4[(size_t)s1 * 64 + lane];
    uint32 v2 = h4[(size_t)s2 * 64 + lane];
    uint32 v3 = h4[(size_t)s3 * 64 + lane];
    ax += bf2f((unsigned short)(v0 & 0xffff)) + bf2f((unsigned short)(v1 & 0xffff)) +
          bf2f((unsigned short)(v2 & 0xffff)) + bf2f((unsigned short)(v3 & 0xffff));
    ay += bf2f((unsigned short)(v0 >> 16)) + bf2f((unsigned short)(v1 >> 16)) +
          bf2f((unsigned short)(v2 >> 16)) + bf2f((unsigned short)(v3 >> 16));
  }
  for (; e < end; e++) {
    int s = esrc[e];
    uint32 v = h4[(size_t)s * 64 + lane];
    ax += bf2f((unsigned short)(v & 0xffff));
    ay += bf2f((unsigned short)(v >> 16));
  }
  float d = d_dst[node];
  float2 b = ((const float2*)bias)[lane];
  float vx = ax * d + b.x;
  float vy = ay * d + b.y;
  if (RES) {
    uint32 r = ((const uint32*)res)[(size_t)node * 64 + lane];
    vx += bf2f((unsigned short)(r & 0xffff));
    vy += bf2f((unsigned short)(r >> 16));
  }
  if (RELU) {
    vx = fmaxf(vx, 0.f);
    vy = fmaxf(vy, 0.f);
  }
  uint32 o = (uint32)f2bf(vx) | ((uint32)f2bf(vy) << 16);
  ((uint32*)out)[(size_t)node * 64 + lane] = o;
}

// ---------------- launch ----------------

extern "C" void kernel_launch(void* const* d_in, const int* in_sizes, int n_in,
                              void* d_out, int out_size, void* d_ws, size_t ws_size,
                              hipStream_t stream) {
  (void)n_in; (void)out_size; (void)ws_size;
  const float* x  = (const float*)d_in[0];
  const int*   src = (const int*)d_in[1];
  const int*   dst = (const int*)d_in[2];
  const float* W1 = (const float*)d_in[3];
  const float* b1 = (const float*)d_in[4];
  const float* W2 = (const float*)d_in[5];
  const float* b2 = (const float*)d_in[6];
  const float* W3 = (const float*)d_in[7];
  const float* b3 = (const float*)d_in[8];
  const float* Wr = (const float*)d_in[9];
  const float* br = (const float*)d_in[10];
  const float* Wo = (const float*)d_in[11];
  const float* bo = (const float*)d_in[12];
  float* out = (float*)d_out;

  const int N = in_sizes[0] / FD;
  const int E = in_sizes[1];

  char* ws = (char*)d_ws;
  size_t off = 0;
  auto alloc = [&](size_t bytes) -> void* {
    void* p = ws + off;
    off += (bytes + 255) & ~size_t(255);
    return p;
  };
  int* histD   = (int*)alloc((size_t)NBINS * NB * 4);
  int* histS   = (int*)alloc((size_t)NBINS * NB * 4);
  int* dstB    = (int*)alloc((size_t)E * 4);
  int* srcB    = (int*)alloc((size_t)E * 4);
  int* srcS    = (int*)alloc((size_t)E * 4);
  int* esrc    = (int*)alloc((size_t)E * 4);
  int* row_ptr = (int*)alloc((size_t)(N + 1) * 4);
  float* d_src = (float*)alloc((size_t)N * 4);
  float* d_dst = (float*)alloc((size_t)N * 4);
  unsigned short* tb0  = (unsigned short*)alloc((size_t)N * FD * 2);
  unsigned short* tb1  = (unsigned short*)alloc((size_t)N * FD * 2);
  unsigned short* resb = (unsigned short*)alloc((size_t)N * FD * 2);

  int chunk = (E + NB - 1) / NB;

  k_hist<<<NB, 256, 0, stream>>>(src, dst, histD, histS, E, chunk);
  k_scan2<<<1, 1024, 0, stream>>>(histD, histS, NBINS * NB);
  k_scatter<<<NB, 256, 0, stream>>>(src, dst, histD, histS, dstB, srcB, srcS, E, chunk);
  k_bucket_dst<<<NBINS, 256, 0, stream>>>(dstB, srcB, histD, esrc, row_ptr, d_dst, N, E);
  k_bucket_src<<<NBINS, 256, 0, stream>>>(srcS, histS, d_src, N, E);

  dim3 g128((N + 63) / 64, 2);
  dim3 g64((N + 63) / 64, 1);
  int gA = (N + 3) / 4;
  const size_t LDS = 49152;

  // res = x @ Wr + br  (bf16 out)
  k_gemm<FD, false, false, true, true><<<g128, 256, LDS, stream>>>(x, Wr, br, nullptr, resb, N);
  // layer 1: h = d_src ⊙ (x @ W1)  (bf16 out)
  k_gemm<FD, false, true, false, true><<<g128, 256, LDS, stream>>>(x, W1, nullptr, d_src, tb0, N);
  k_agg<true, false><<<gA, 256, 0, stream>>>(tb0, row_ptr, esrc, d_dst, b1, nullptr, tb1, N);
  // layer 2
  k_gemm<FD, true, true, false, true><<<g128, 256, LDS, stream>>>(tb1, W2, nullptr, d_src, tb0, N);
  k_agg<true, false><<<gA, 256, 0, stream>>>(tb0, row_ptr, esrc, d_dst, b2, nullptr, tb1, N);
  // layer 3 + residual + relu
  k_gemm<FD, true, true, false, true><<<g128, 256, LDS, stream>>>(tb1, W3, nullptr, d_src, tb0, N);
  k_agg<true, true><<<gA, 256, 0, stream>>>(tb0, row_ptr, esrc, d_dst, b3, resb, tb1, N);
  // out = t1 @ Wo + bo  (fp32 out)
  k_gemm<CO, true, false, true, false><<<g64, 256, LDS, stream>>>(tb1, Wo, bo, nullptr, out, N);
}

// Round 6
// 256.617 us; speedup vs baseline: 1.7159x; 1.7159x over previous
//
#include <hip/hip_runtime.h>
#include <cstdint>
#include <cstddef>

#define FD 128
#define CO 64
#define NB 256     // partition blocks
#define NBINS 256  // buckets (node>>8); requires N <= 65536

typedef short bf16x8 __attribute__((ext_vector_type(8)));
typedef float f32x4 __attribute__((ext_vector_type(4)));
typedef unsigned int uint32;

__device__ __forceinline__ unsigned short f2bf(float f) {
  unsigned u = __float_as_uint(f);
  unsigned r = u + 0x7fffu + ((u >> 16) & 1u);
  return (unsigned short)(r >> 16);
}
__device__ __forceinline__ float bf2f(unsigned short b) {
  return __uint_as_float((unsigned)b << 16);
}

// ---------------- CSR build: scan-based counting sort (no global atomics) ----------------

// per-block 256-bin LDS histograms of dst>>8 and src>>8
__global__ __launch_bounds__(256) void k_hist(const int* __restrict__ src,
                                              const int* __restrict__ dst,
                                              int* __restrict__ histD,
                                              int* __restrict__ histS,
                                              int E, int chunk) {
  __shared__ int hd[NBINS], hs[NBINS];
  int tid = threadIdx.x, blk = blockIdx.x;
  hd[tid] = 0;
  hs[tid] = 0;
  __syncthreads();
  int beg = blk * chunk;
  int end = min(E, beg + chunk);
  for (int e = beg + tid; e < end; e += 256) {
    atomicAdd(&hd[dst[e] >> 8], 1);
    atomicAdd(&hs[src[e] >> 8], 1);
  }
  __syncthreads();
  histD[tid * NB + blk] = hd[tid];  // bin-major layout
  histS[tid * NB + blk] = hs[tid];
}

// ---- 3-phase multi-block exclusive scan of histD & histS (grid.y picks array) ----

// phase 1: per-256-chunk sums
__global__ __launch_bounds__(256) void k_ssum(int* __restrict__ a,
                                              int* __restrict__ b,
                                              int* __restrict__ bsums) {
  const int* p = blockIdx.y ? b : a;
  __shared__ int red[256];
  int tid = threadIdx.x;
  red[tid] = p[blockIdx.x * 256 + tid];
  __syncthreads();
  for (int o = 128; o > 0; o >>= 1) {
    if (tid < o) red[tid] += red[tid + o];
    __syncthreads();
  }
  if (tid == 0) bsums[blockIdx.y * 256 + blockIdx.x] = red[0];
}

// phase 2: exclusive scan of both 256-entry rows (one block)
__global__ __launch_bounds__(256) void k_sscan(int* __restrict__ bsums) {
  __shared__ int s[256];
  int tid = threadIdx.x;
  for (int r = 0; r < 2; r++) {
    int v = bsums[r * 256 + tid];
    s[tid] = v;
    __syncthreads();
    for (int o = 1; o < 256; o <<= 1) {
      int t = (tid >= o) ? s[tid - o] : 0;
      __syncthreads();
      s[tid] += t;
      __syncthreads();
    }
    bsums[r * 256 + tid] = s[tid] - v;  // exclusive
    __syncthreads();
  }
}

// phase 3: per-chunk exclusive scan + block offset, in place
__global__ __launch_bounds__(256) void k_sapply(int* __restrict__ a,
                                                int* __restrict__ b,
                                                const int* __restrict__ bsums) {
  int* p = blockIdx.y ? b : a;
  int boff = bsums[blockIdx.y * 256 + blockIdx.x];
  __shared__ int s[256];
  int tid = threadIdx.x;
  int i = blockIdx.x * 256 + tid;
  int v = p[i];
  s[tid] = v;
  __syncthreads();
  for (int o = 1; o < 256; o <<= 1) {
    int t = (tid >= o) ? s[tid - o] : 0;
    __syncthreads();
    s[tid] += t;
    __syncthreads();
  }
  p[i] = boff + s[tid] - v;
}

// partition edges into dst-buckets (dstB,srcB) and src ids into src-buckets (srcS)
__global__ __launch_bounds__(256) void k_scatter(const int* __restrict__ src,
                                                 const int* __restrict__ dst,
                                                 const int* __restrict__ offD,
                                                 const int* __restrict__ offS,
                                                 int* __restrict__ dstB,
                                                 int* __restrict__ srcB,
                                                 int* __restrict__ srcS,
                                                 int E, int chunk) {
  __shared__ int runD[NBINS], runS[NBINS];
  int tid = threadIdx.x, blk = blockIdx.x;
  runD[tid] = offD[tid * NB + blk];
  runS[tid] = offS[tid * NB + blk];
  __syncthreads();
  int beg = blk * chunk;
  int end = min(E, beg + chunk);
  for (int e = beg + tid; e < end; e += 256) {
    int s = src[e], d = dst[e];
    int p = atomicAdd(&runD[d >> 8], 1);
    dstB[p] = d;
    srcB[p] = s;
    int q = atomicAdd(&runS[s >> 8], 1);
    srcS[q] = s;
  }
}

// per-bucket: count deg_in -> row_ptr, d_dst; scatter srcB into final CSR esrc
__global__ __launch_bounds__(256) void k_bucket_dst(const int* __restrict__ dstB,
                                                    const int* __restrict__ srcB,
                                                    const int* __restrict__ offD,
                                                    int* __restrict__ esrc,
                                                    int* __restrict__ row_ptr,
                                                    float* __restrict__ d_dst,
                                                    int N, int E) {
  __shared__ int cnt[NBINS], run[NBINS];
  int tid = threadIdx.x, bin = blockIdx.x;
  int start = offD[bin * NB];
  int end = (bin == NBINS - 1) ? E : offD[(bin + 1) * NB];
  cnt[tid] = 0;
  __syncthreads();
  for (int p = start + tid; p < end; p += 256) atomicAdd(&cnt[dstB[p] & 255], 1);
  __syncthreads();
  int v = cnt[tid];
  run[tid] = v;
  __syncthreads();
  for (int o = 1; o < 256; o <<= 1) {
    int t = (tid >= o) ? run[tid - o] : 0;
    __syncthreads();
    run[tid] += t;
    __syncthreads();
  }
  int excl = run[tid] - v;
  int node = bin * 256 + tid;
  if (node < N) {
    row_ptr[node] = start + excl;
    d_dst[node] = rsqrtf((float)(v > 0 ? v : 1));
  }
  __syncthreads();
  run[tid] = start + excl;  // reuse as scatter cursor
  __syncthreads();
  for (int p = start + tid; p < end; p += 256) {
    int d = dstB[p];
    int slot = atomicAdd(&run[d & 255], 1);
    esrc[slot] = srcB[p];
  }
  if (bin == 0 && tid == 0) row_ptr[N] = E;
}

// per-bucket: count deg_out -> d_src
__global__ __launch_bounds__(256) void k_bucket_src(const int* __restrict__ srcS,
                                                    const int* __restrict__ offS,
                                                    float* __restrict__ d_src,
                                                    int N, int E) {
  __shared__ int cnt[NBINS];
  int tid = threadIdx.x, bin = blockIdx.x;
  int start = offS[bin * NB];
  int end = (bin == NBINS - 1) ? E : offS[(bin + 1) * NB];
  cnt[tid] = 0;
  __syncthreads();
  for (int p = start + tid; p < end; p += 256) atomicAdd(&cnt[srcS[p] & 255], 1);
  __syncthreads();
  int node = bin * 256 + tid;
  if (node < N) {
    int v = cnt[tid];
    d_src[node] = rsqrtf((float)(v > 0 ? v : 1));
  }
}

// ---------------- MFMA GEMM ----------------
// A: bf16 [N][128] (ABF16) or fp32 (rounded to bf16 at staging).
// W: fp32, split hi/lo bf16 (weight error ~2^-18).
// epilogue: v = acc * (SCALE ? rscale[row] : 1) + (BIAS ? bias[col] : 0).

template <int NCW, bool ABF16, bool SCALE, bool BIAS, bool OUTBF16>
__global__ __launch_bounds__(256) void k_gemm(const void* __restrict__ Av,
                                              const float* __restrict__ W,
                                              const float* __restrict__ bias,
                                              const float* __restrict__ rscale,
                                              void* __restrict__ outv, int N) {
  extern __shared__ char smem[];
  bf16x8* Ah = (bf16x8*)smem;   // [16 kc][64 row] 16B slots = 16KB
  bf16x8* Wh = Ah + 1024;       // [16 kc][64 col] 16KB
  bf16x8* Wl = Wh + 1024;       // 16KB
  int tid = threadIdx.x;
  int rowBase = blockIdx.x * 64;
  int colBase = blockIdx.y * 64;

#pragma unroll
  for (int t = 0; t < 4; t++) {
    int p = t * 256 + tid;
    int kc = p >> 6, col = p & 63;
    bf16x8 h, l;
#pragma unroll
    for (int j = 0; j < 8; j++) {
      float v = W[(size_t)(kc * 8 + j) * NCW + colBase + col];
      unsigned short hb = f2bf(v);
      h[j] = (short)hb;
      l[j] = (short)f2bf(v - bf2f(hb));
    }
    Wh[kc * 64 + col] = h;
    Wl[kc * 64 + col] = l;
  }
#pragma unroll
  for (int t = 0; t < 4; t++) {
    int p = t * 256 + tid;
    int kc = p >> 6, row = p & 63;
    int gr = rowBase + row;
    bf16x8 h = {0, 0, 0, 0, 0, 0, 0, 0};
    if (gr < N) {
      if (ABF16) {
        h = *(const bf16x8*)((const unsigned short*)Av + (size_t)gr * FD + kc * 8);
      } else {
        const float4* A4 = (const float4*)((const float*)Av + (size_t)gr * FD + kc * 8);
        float4 u = A4[0];
        float4 v = A4[1];
        float vals[8] = {u.x, u.y, u.z, u.w, v.x, v.y, v.z, v.w};
#pragma unroll
        for (int j = 0; j < 8; j++) h[j] = (short)f2bf(vals[j]);
      }
    }
    Ah[kc * 64 + row] = h;
  }
  __syncthreads();

  int wv = tid >> 6, lane = tid & 63;
  int wr = (wv >> 1) * 32, wc = (wv & 1) * 32;
  int lhi = lane >> 4, llo = lane & 15;
  f32x4 acc[2][2] = {};

#pragma unroll
  for (int ks = 0; ks < 4; ks++) {
    int kcg = ks * 4 + lhi;
    int abase = kcg * 64 + wr + llo;
    int bbase = kcg * 64 + wc + llo;
    bf16x8 a0 = Ah[abase];
    bf16x8 a1 = Ah[abase + 16];
    bf16x8 bh0 = Wh[bbase];
    bf16x8 bh1 = Wh[bbase + 16];
    bf16x8 bl0 = Wl[bbase];
    bf16x8 bl1 = Wl[bbase + 16];
    acc[0][0] = __builtin_amdgcn_mfma_f32_16x16x32_bf16(a0, bh0, acc[0][0], 0, 0, 0);
    acc[0][1] = __builtin_amdgcn_mfma_f32_16x16x32_bf16(a0, bh1, acc[0][1], 0, 0, 0);
    acc[1][0] = __builtin_amdgcn_mfma_f32_16x16x32_bf16(a1, bh0, acc[1][0], 0, 0, 0);
    acc[1][1] = __builtin_amdgcn_mfma_f32_16x16x32_bf16(a1, bh1, acc[1][1], 0, 0, 0);
    acc[0][0] = __builtin_amdgcn_mfma_f32_16x16x32_bf16(a0, bl0, acc[0][0], 0, 0, 0);
    acc[0][1] = __builtin_amdgcn_mfma_f32_16x16x32_bf16(a0, bl1, acc[0][1], 0, 0, 0);
    acc[1][0] = __builtin_amdgcn_mfma_f32_16x16x32_bf16(a1, bl0, acc[1][0], 0, 0, 0);
    acc[1][1] = __builtin_amdgcn_mfma_f32_16x16x32_bf16(a1, bl1, acc[1][1], 0, 0, 0);
  }

  float bv0 = 0.f, bv1 = 0.f;
  if (BIAS) {
    bv0 = bias[colBase + wc + llo];
    bv1 = bias[colBase + wc + 16 + llo];
  }
  float rs[2][4];
  if (SCALE) {
#pragma unroll
    for (int mf = 0; mf < 2; mf++)
#pragma unroll
      for (int r = 0; r < 4; r++) {
        int row = rowBase + wr + mf * 16 + lhi * 4 + r;
        rs[mf][r] = (row < N) ? rscale[row] : 0.f;
      }
  }
#pragma unroll
  for (int mf = 0; mf < 2; mf++) {
#pragma unroll
    for (int nf = 0; nf < 2; nf++) {
      float bv = nf ? bv1 : bv0;
      int col = colBase + wc + nf * 16 + llo;
#pragma unroll
      for (int r = 0; r < 4; r++) {
        int row = rowBase + wr + mf * 16 + lhi * 4 + r;
        if (row < N) {
          float v = acc[mf][nf][r];
          if (SCALE) v *= rs[mf][r];
          v += bv;
          if (OUTBF16)
            ((unsigned short*)outv)[(size_t)row * NCW + col] = f2bf(v);
          else
            ((float*)outv)[(size_t)row * NCW + col] = v;
        }
      }
    }
  }
}

// ---------------- Aggregation (bf16 rows) ----------------

template <bool RELU, bool RES>
__global__ __launch_bounds__(256) void k_agg(const unsigned short* __restrict__ h,
                                             const int* __restrict__ row_ptr,
                                             const int* __restrict__ esrc,
                                             const float* __restrict__ d_dst,
                                             const float* __restrict__ bias,
                                             const unsigned short* __restrict__ res,
                                             unsigned short* __restrict__ out, int N) {
  int node = blockIdx.x * 4 + (threadIdx.x >> 6);
  int lane = threadIdx.x & 63;
  if (node >= N) return;
  int beg = row_ptr[node], end = row_ptr[node + 1];
  const uint32* h4 = (const uint32*)h;
  float ax = 0.f, ay = 0.f;
  int e = beg;
  for (; e + 4 <= end; e += 4) {
    int s0 = esrc[e + 0];
    int s1 = esrc[e + 1];
    int s2 = esrc[e + 2];
    int s3 = esrc[e + 3];
    uint32 v0 = h4[(size_t)s0 * 64 + lane];
    uint32 v1 = h4[(size_t)s1 * 64 + lane];
    uint32 v2 = h4[(size_t)s2 * 64 + lane];
    uint32 v3 = h4[(size_t)s3 * 64 + lane];
    ax += bf2f((unsigned short)(v0 & 0xffff)) + bf2f((unsigned short)(v1 & 0xffff)) +
          bf2f((unsigned short)(v2 & 0xffff)) + bf2f((unsigned short)(v3 & 0xffff));
    ay += bf2f((unsigned short)(v0 >> 16)) + bf2f((unsigned short)(v1 >> 16)) +
          bf2f((unsigned short)(v2 >> 16)) + bf2f((unsigned short)(v3 >> 16));
  }
  for (; e < end; e++) {
    int s = esrc[e];
    uint32 v = h4[(size_t)s * 64 + lane];
    ax += bf2f((unsigned short)(v & 0xffff));
    ay += bf2f((unsigned short)(v >> 16));
  }
  float d = d_dst[node];
  float2 b = ((const float2*)bias)[lane];
  float vx = ax * d + b.x;
  float vy = ay * d + b.y;
  if (RES) {
    uint32 r = ((const uint32*)res)[(size_t)node * 64 + lane];
    vx += bf2f((unsigned short)(r & 0xffff));
    vy += bf2f((unsigned short)(r >> 16));
  }
  if (RELU) {
    vx = fmaxf(vx, 0.f);
    vy = fmaxf(vy, 0.f);
  }
  uint32 o = (uint32)f2bf(vx) | ((uint32)f2bf(vy) << 16);
  ((uint32*)out)[(size_t)node * 64 + lane] = o;
}

// ---------------- launch ----------------

extern "C" void kernel_launch(void* const* d_in, const int* in_sizes, int n_in,
                              void* d_out, int out_size, void* d_ws, size_t ws_size,
                              hipStream_t stream) {
  (void)n_in; (void)out_size; (void)ws_size;
  const float* x  = (const float*)d_in[0];
  const int*   src = (const int*)d_in[1];
  const int*   dst = (const int*)d_in[2];
  const float* W1 = (const float*)d_in[3];
  const float* b1 = (const float*)d_in[4];
  const float* W2 = (const float*)d_in[5];
  const float* b2 = (const float*)d_in[6];
  const float* W3 = (const float*)d_in[7];
  const float* b3 = (const float*)d_in[8];
  const float* Wr = (const float*)d_in[9];
  const float* br = (const float*)d_in[10];
  const float* Wo = (const float*)d_in[11];
  const float* bo = (const float*)d_in[12];
  float* out = (float*)d_out;

  const int N = in_sizes[0] / FD;
  const int E = in_sizes[1];

  char* ws = (char*)d_ws;
  size_t off = 0;
  auto alloc = [&](size_t bytes) -> void* {
    void* p = ws + off;
    off += (bytes + 255) & ~size_t(255);
    return p;
  };
  int* histD   = (int*)alloc((size_t)NBINS * NB * 4);
  int* histS   = (int*)alloc((size_t)NBINS * NB * 4);
  int* bsums   = (int*)alloc(2 * 256 * 4);
  int* dstB    = (int*)alloc((size_t)E * 4);
  int* srcB    = (int*)alloc((size_t)E * 4);
  int* srcS    = (int*)alloc((size_t)E * 4);
  int* esrc    = (int*)alloc((size_t)E * 4);
  int* row_ptr = (int*)alloc((size_t)(N + 1) * 4);
  float* d_src = (float*)alloc((size_t)N * 4);
  float* d_dst = (float*)alloc((size_t)N * 4);
  unsigned short* tb0  = (unsigned short*)alloc((size_t)N * FD * 2);
  unsigned short* tb1  = (unsigned short*)alloc((size_t)N * FD * 2);
  unsigned short* resb = (unsigned short*)alloc((size_t)N * FD * 2);

  int chunk = (E + NB - 1) / NB;
  dim3 gScan(256, 2);

  k_hist<<<NB, 256, 0, stream>>>(src, dst, histD, histS, E, chunk);
  k_ssum<<<gScan, 256, 0, stream>>>(histD, histS, bsums);
  k_sscan<<<1, 256, 0, stream>>>(bsums);
  k_sapply<<<gScan, 256, 0, stream>>>(histD, histS, bsums);
  k_scatter<<<NB, 256, 0, stream>>>(src, dst, histD, histS, dstB, srcB, srcS, E, chunk);
  k_bucket_dst<<<NBINS, 256, 0, stream>>>(dstB, srcB, histD, esrc, row_ptr, d_dst, N, E);
  k_bucket_src<<<NBINS, 256, 0, stream>>>(srcS, histS, d_src, N, E);

  dim3 g128((N + 63) / 64, 2);
  dim3 g64((N + 63) / 64, 1);
  int gA = (N + 3) / 4;
  const size_t LDS = 49152;

  // res = x @ Wr + br  (bf16 out)
  k_gemm<FD, false, false, true, true><<<g128, 256, LDS, stream>>>(x, Wr, br, nullptr, resb, N);
  // layer 1: h = d_src ⊙ (x @ W1)  (bf16 out)
  k_gemm<FD, false, true, false, true><<<g128, 256, LDS, stream>>>(x, W1, nullptr, d_src, tb0, N);
  k_agg<true, false><<<gA, 256, 0, stream>>>(tb0, row_ptr, esrc, d_dst, b1, nullptr, tb1, N);
  // layer 2
  k_gemm<FD, true, true, false, true><<<g128, 256, LDS, stream>>>(tb1, W2, nullptr, d_src, tb0, N);
  k_agg<true, false><<<gA, 256, 0, stream>>>(tb0, row_ptr, esrc, d_dst, b2, nullptr, tb1, N);
  // layer 3 + residual + relu
  k_gemm<FD, true, true, false, true><<<g128, 256, LDS, stream>>>(tb1, W3, nullptr, d_src, tb0, N);
  k_agg<true, true><<<gA, 256, 0, stream>>>(tb0, row_ptr, esrc, d_dst, b3, resb, tb1, N);
  // out = t1 @ Wo + bo  (fp32 out)
  k_gemm<CO, true, false, true, false><<<g64, 256, LDS, stream>>>(tb1, Wo, bo, nullptr, out, N);
}

// Round 7
// 246.130 us; speedup vs baseline: 1.7890x; 1.0426x over previous
//
#include <hip/hip_runtime.h>
#include <cstdint>
#include <cstddef>

#define FD 128
#define CO 64
#define NB 256     // partition blocks
#define NBINS 256  // buckets (node>>8); requires N <= 65536, src < 2^24

typedef short bf16x8 __attribute__((ext_vector_type(8)));
typedef float f32x4 __attribute__((ext_vector_type(4)));
typedef unsigned int uint32;
typedef unsigned char uint8;

__device__ __forceinline__ unsigned short f2bf(float f) {
  unsigned u = __float_as_uint(f);
  unsigned r = u + 0x7fffu + ((u >> 16) & 1u);
  return (unsigned short)(r >> 16);
}
__device__ __forceinline__ float bf2f(unsigned short b) {
  return __uint_as_float((unsigned)b << 16);
}

// ---------------- CSR build: scan-based counting sort (no global atomics) ----------------

__global__ __launch_bounds__(256) void k_hist(const int* __restrict__ src,
                                              const int* __restrict__ dst,
                                              int* __restrict__ histD,
                                              int* __restrict__ histS,
                                              int E, int chunk) {
  __shared__ int hd[NBINS], hs[NBINS];
  int tid = threadIdx.x, blk = blockIdx.x;
  hd[tid] = 0;
  hs[tid] = 0;
  __syncthreads();
  int beg = blk * chunk;
  int end = min(E, beg + chunk);
  for (int e = beg + tid; e < end; e += 256) {
    atomicAdd(&hd[dst[e] >> 8], 1);
    atomicAdd(&hs[src[e] >> 8], 1);
  }
  __syncthreads();
  histD[tid * NB + blk] = hd[tid];  // bin-major layout
  histS[tid * NB + blk] = hs[tid];
}

// ---- 3-phase multi-block exclusive scan of histD & histS (grid.y picks array) ----

__global__ __launch_bounds__(256) void k_ssum(int* __restrict__ a,
                                              int* __restrict__ b,
                                              int* __restrict__ bsums) {
  const int* p = blockIdx.y ? b : a;
  __shared__ int red[256];
  int tid = threadIdx.x;
  red[tid] = p[blockIdx.x * 256 + tid];
  __syncthreads();
  for (int o = 128; o > 0; o >>= 1) {
    if (tid < o) red[tid] += red[tid + o];
    __syncthreads();
  }
  if (tid == 0) bsums[blockIdx.y * 256 + blockIdx.x] = red[0];
}

__global__ __launch_bounds__(256) void k_sscan(int* __restrict__ bsums) {
  __shared__ int s[256];
  int tid = threadIdx.x;
  for (int r = 0; r < 2; r++) {
    int v = bsums[r * 256 + tid];
    s[tid] = v;
    __syncthreads();
    for (int o = 1; o < 256; o <<= 1) {
      int t = (tid >= o) ? s[tid - o] : 0;
      __syncthreads();
      s[tid] += t;
      __syncthreads();
    }
    bsums[r * 256 + tid] = s[tid] - v;  // exclusive
    __syncthreads();
  }
}

__global__ __launch_bounds__(256) void k_sapply(int* __restrict__ a,
                                                int* __restrict__ b,
                                                const int* __restrict__ bsums) {
  int* p = blockIdx.y ? b : a;
  int boff = bsums[blockIdx.y * 256 + blockIdx.x];
  __shared__ int s[256];
  int tid = threadIdx.x;
  int i = blockIdx.x * 256 + tid;
  int v = p[i];
  s[tid] = v;
  __syncthreads();
  for (int o = 1; o < 256; o <<= 1) {
    int t = (tid >= o) ? s[tid - o] : 0;
    __syncthreads();
    s[tid] += t;
    __syncthreads();
  }
  p[i] = boff + s[tid] - v;
}

// partition edges into dst-buckets (packed (src<<8)|dlow) and src low-bytes into src-buckets
__global__ __launch_bounds__(256) void k_scatter(const int* __restrict__ src,
                                                 const int* __restrict__ dst,
                                                 const int* __restrict__ offD,
                                                 const int* __restrict__ offS,
                                                 uint32* __restrict__ pk,
                                                 uint8* __restrict__ srcS8,
                                                 int E, int chunk) {
  __shared__ int runD[NBINS], runS[NBINS];
  int tid = threadIdx.x, blk = blockIdx.x;
  runD[tid] = offD[tid * NB + blk];
  runS[tid] = offS[tid * NB + blk];
  __syncthreads();
  int beg = blk * chunk;
  int end = min(E, beg + chunk);
  for (int e = beg + tid; e < end; e += 256) {
    int s = src[e], d = dst[e];
    int p = atomicAdd(&runD[d >> 8], 1);
    pk[p] = ((uint32)s << 8) | (uint32)(d & 255);
    int q = atomicAdd(&runS[s >> 8], 1);
    srcS8[q] = (uint8)(s & 255);
  }
}

// per-bucket: count deg_in -> row_ptr, d_dst; scatter src ids into final CSR esrc
__global__ __launch_bounds__(256) void k_bucket_dst(const uint32* __restrict__ pk,
                                                    const int* __restrict__ offD,
                                                    int* __restrict__ esrc,
                                                    int* __restrict__ row_ptr,
                                                    float* __restrict__ d_dst,
                                                    int N, int E) {
  __shared__ int cnt[NBINS], run[NBINS];
  int tid = threadIdx.x, bin = blockIdx.x;
  int start = offD[bin * NB];
  int end = (bin == NBINS - 1) ? E : offD[(bin + 1) * NB];
  cnt[tid] = 0;
  __syncthreads();
  for (int p = start + tid; p < end; p += 256) atomicAdd(&cnt[pk[p] & 255], 1);
  __syncthreads();
  int v = cnt[tid];
  run[tid] = v;
  __syncthreads();
  for (int o = 1; o < 256; o <<= 1) {
    int t = (tid >= o) ? run[tid - o] : 0;
    __syncthreads();
    run[tid] += t;
    __syncthreads();
  }
  int excl = run[tid] - v;
  int node = bin * 256 + tid;
  if (node < N) {
    row_ptr[node] = start + excl;
    d_dst[node] = rsqrtf((float)(v > 0 ? v : 1));
  }
  __syncthreads();
  run[tid] = start + excl;  // reuse as scatter cursor
  __syncthreads();
  for (int p = start + tid; p < end; p += 256) {
    uint32 v2 = pk[p];
    int slot = atomicAdd(&run[v2 & 255], 1);
    esrc[slot] = (int)(v2 >> 8);
  }
  if (bin == 0 && tid == 0) row_ptr[N] = E;
}

// per-bucket: count deg_out -> d_src
__global__ __launch_bounds__(256) void k_bucket_src(const uint8* __restrict__ srcS8,
                                                    const int* __restrict__ offS,
                                                    float* __restrict__ d_src,
                                                    int N, int E) {
  __shared__ int cnt[NBINS];
  int tid = threadIdx.x, bin = blockIdx.x;
  int start = offS[bin * NB];
  int end = (bin == NBINS - 1) ? E : offS[(bin + 1) * NB];
  cnt[tid] = 0;
  __syncthreads();
  for (int p = start + tid; p < end; p += 256) atomicAdd(&cnt[srcS8[p]], 1);
  __syncthreads();
  int node = bin * 256 + tid;
  if (node < N) {
    int v = cnt[tid];
    d_src[node] = rsqrtf((float)(v > 0 ? v : 1));
  }
}

// ---------------- weight pre-split: fp32 -> frag-packed bf16 hi/lo ----------------
// layout: slot = kc*cols + col holds 8 bf16 for elements (kc*8+j, col).
// regions: 0..3 -> W1,W2,W3,Wr (128x128, 2048 slots each); 4 -> Wo (128x64, 1024).

__global__ __launch_bounds__(256) void k_wsplit(const float* __restrict__ W1,
                                                const float* __restrict__ W2,
                                                const float* __restrict__ W3,
                                                const float* __restrict__ Wr,
                                                const float* __restrict__ Wo,
                                                bf16x8* __restrict__ Whg,
                                                bf16x8* __restrict__ Wlg) {
  int idx = blockIdx.x * 256 + threadIdx.x;  // 9216 slots total
  if (idx >= 9216) return;
  int region = idx >> 11;            // 0..4 (idx<8192 -> 0..3, else 4)
  if (idx >= 8192) region = 4;
  const float* W = (region == 0) ? W1 : (region == 1) ? W2 : (region == 2) ? W3
                   : (region == 3) ? Wr : Wo;
  int cols = (region < 4) ? FD : CO;
  int local = idx - region * 2048;
  int kc = local / cols, col = local - kc * cols;
  bf16x8 h, l;
#pragma unroll
  for (int j = 0; j < 8; j++) {
    float v = W[(size_t)(kc * 8 + j) * cols + col];
    unsigned short hb = f2bf(v);
    h[j] = (short)hb;
    l[j] = (short)f2bf(v - bf2f(hb));
  }
  Whg[idx] = h;
  Wlg[idx] = l;
}

// ---------------- MFMA GEMM (full-width tile, W frags direct from global) ----------------
// tile: 64 rows x NCW cols per block. 4 waves as 2x2; wave-tile 32 x NCW/2.
// A staged in LDS (16KB, frag-packed). B frags read from pre-split global tables
// (L1/L2-hot, coalesced 16B/lane).

template <int NCW, bool ABF16, bool SCALE, bool BIAS, bool OUTBF16>
__global__ __launch_bounds__(256) void k_gemm(const void* __restrict__ Av,
                                              const bf16x8* __restrict__ Wh,
                                              const bf16x8* __restrict__ Wl,
                                              const float* __restrict__ bias,
                                              const float* __restrict__ rscale,
                                              void* __restrict__ outv, int N) {
  constexpr int NF = NCW / 32;  // col-frags per wave
  __shared__ bf16x8 Ah[1024];   // [16 kc][64 row]
  int tid = threadIdx.x;
  int rowBase = blockIdx.x * 64;

  // stage A tile (bf16 passthrough or fp32 -> bf16 round)
#pragma unroll
  for (int t = 0; t < 4; t++) {
    int p = t * 256 + tid;
    int kc = p >> 6, row = p & 63;
    int gr = rowBase + row;
    bf16x8 h = {0, 0, 0, 0, 0, 0, 0, 0};
    if (gr < N) {
      if (ABF16) {
        h = *(const bf16x8*)((const unsigned short*)Av + (size_t)gr * FD + kc * 8);
      } else {
        const float4* A4 = (const float4*)((const float*)Av + (size_t)gr * FD + kc * 8);
        float4 u = A4[0];
        float4 v = A4[1];
        float vals[8] = {u.x, u.y, u.z, u.w, v.x, v.y, v.z, v.w};
#pragma unroll
        for (int j = 0; j < 8; j++) h[j] = (short)f2bf(vals[j]);
      }
    }
    Ah[kc * 64 + row] = h;
  }
  __syncthreads();

  int wv = tid >> 6, lane = tid & 63;
  int wr = (wv >> 1) * 32;
  int wc = (wv & 1) * (NCW / 2);
  int lhi = lane >> 4, llo = lane & 15;
  f32x4 acc[2][NF] = {};

#pragma unroll
  for (int ks = 0; ks < 4; ks++) {
    int kcg = ks * 4 + lhi;
    int abase = kcg * 64 + wr + llo;
    bf16x8 a0 = Ah[abase];
    bf16x8 a1 = Ah[abase + 16];
    int bbase = kcg * NCW + wc + llo;
#pragma unroll
    for (int nf = 0; nf < NF; nf++) {
      bf16x8 bh = Wh[bbase + nf * 16];
      bf16x8 bl = Wl[bbase + nf * 16];
      acc[0][nf] = __builtin_amdgcn_mfma_f32_16x16x32_bf16(a0, bh, acc[0][nf], 0, 0, 0);
      acc[1][nf] = __builtin_amdgcn_mfma_f32_16x16x32_bf16(a1, bh, acc[1][nf], 0, 0, 0);
      acc[0][nf] = __builtin_amdgcn_mfma_f32_16x16x32_bf16(a0, bl, acc[0][nf], 0, 0, 0);
      acc[1][nf] = __builtin_amdgcn_mfma_f32_16x16x32_bf16(a1, bl, acc[1][nf], 0, 0, 0);
    }
  }

  // epilogue: C/D layout col=lane&15, row=(lane>>4)*4+reg
  float rs[2][4];
  if (SCALE) {
#pragma unroll
    for (int mf = 0; mf < 2; mf++)
#pragma unroll
      for (int r = 0; r < 4; r++) {
        int row = rowBase + wr + mf * 16 + lhi * 4 + r;
        rs[mf][r] = (row < N) ? rscale[row] : 0.f;
      }
  }
#pragma unroll
  for (int nf = 0; nf < NF; nf++) {
    int col = wc + nf * 16 + llo;
    float bv = BIAS ? bias[col] : 0.f;
#pragma unroll
    for (int mf = 0; mf < 2; mf++) {
#pragma unroll
      for (int r = 0; r < 4; r++) {
        int row = rowBase + wr + mf * 16 + lhi * 4 + r;
        if (row < N) {
          float v = acc[mf][nf][r];
          if (SCALE) v *= rs[mf][r];
          v += bv;
          if (OUTBF16)
            ((unsigned short*)outv)[(size_t)row * NCW + col] = f2bf(v);
          else
            ((float*)outv)[(size_t)row * NCW + col] = v;
        }
      }
    }
  }
}

// ---------------- Aggregation (bf16 rows) ----------------

template <bool RELU, bool RES>
__global__ __launch_bounds__(256) void k_agg(const unsigned short* __restrict__ h,
                                             const int* __restrict__ row_ptr,
                                             const int* __restrict__ esrc,
                                             const float* __restrict__ d_dst,
                                             const float* __restrict__ bias,
                                             const unsigned short* __restrict__ res,
                                             unsigned short* __restrict__ out, int N) {
  int node = blockIdx.x * 4 + (threadIdx.x >> 6);
  int lane = threadIdx.x & 63;
  if (node >= N) return;
  int beg = row_ptr[node], end = row_ptr[node + 1];
  const uint32* h4 = (const uint32*)h;
  float ax = 0.f, ay = 0.f;
  int e = beg;
  for (; e + 4 <= end; e += 4) {
    int s0 = esrc[e + 0];
    int s1 = esrc[e + 1];
    int s2 = esrc[e + 2];
    int s3 = esrc[e + 3];
    uint32 v0 = h4[(size_t)s0 * 64 + lane];
    uint32 v1 = h4[(size_t)s1 * 64 + lane];
    uint32 v2 = h4[(size_t)s2 * 64 + lane];
    uint32 v3 = h4[(size_t)s3 * 64 + lane];
    ax += bf2f((unsigned short)(v0 & 0xffff)) + bf2f((unsigned short)(v1 & 0xffff)) +
          bf2f((unsigned short)(v2 & 0xffff)) + bf2f((unsigned short)(v3 & 0xffff));
    ay += bf2f((unsigned short)(v0 >> 16)) + bf2f((unsigned short)(v1 >> 16)) +
          bf2f((unsigned short)(v2 >> 16)) + bf2f((unsigned short)(v3 >> 16));
  }
  for (; e < end; e++) {
    int s = esrc[e];
    uint32 v = h4[(size_t)s * 64 + lane];
    ax += bf2f((unsigned short)(v & 0xffff));
    ay += bf2f((unsigned short)(v >> 16));
  }
  float d = d_dst[node];
  float2 b = ((const float2*)bias)[lane];
  float vx = ax * d + b.x;
  float vy = ay * d + b.y;
  if (RES) {
    uint32 r = ((const uint32*)res)[(size_t)node * 64 + lane];
    vx += bf2f((unsigned short)(r & 0xffff));
    vy += bf2f((unsigned short)(r >> 16));
  }
  if (RELU) {
    vx = fmaxf(vx, 0.f);
    vy = fmaxf(vy, 0.f);
  }
  uint32 o = (uint32)f2bf(vx) | ((uint32)f2bf(vy) << 16);
  ((uint32*)out)[(size_t)node * 64 + lane] = o;
}

// ---------------- launch ----------------

extern "C" void kernel_launch(void* const* d_in, const int* in_sizes, int n_in,
                              void* d_out, int out_size, void* d_ws, size_t ws_size,
                              hipStream_t stream) {
  (void)n_in; (void)out_size; (void)ws_size;
  const float* x  = (const float*)d_in[0];
  const int*   src = (const int*)d_in[1];
  const int*   dst = (const int*)d_in[2];
  const float* W1 = (const float*)d_in[3];
  const float* b1 = (const float*)d_in[4];
  const float* W2 = (const float*)d_in[5];
  const float* b2 = (const float*)d_in[6];
  const float* W3 = (const float*)d_in[7];
  const float* b3 = (const float*)d_in[8];
  const float* Wr = (const float*)d_in[9];
  const float* br = (const float*)d_in[10];
  const float* Wo = (const float*)d_in[11];
  const float* bo = (const float*)d_in[12];
  float* out = (float*)d_out;

  const int N = in_sizes[0] / FD;
  const int E = in_sizes[1];

  char* ws = (char*)d_ws;
  size_t off = 0;
  auto alloc = [&](size_t bytes) -> void* {
    void* p = ws + off;
    off += (bytes + 255) & ~size_t(255);
    return p;
  };
  int* histD   = (int*)alloc((size_t)NBINS * NB * 4);
  int* histS   = (int*)alloc((size_t)NBINS * NB * 4);
  int* bsums   = (int*)alloc(2 * 256 * 4);
  uint32* pk   = (uint32*)alloc((size_t)E * 4);
  uint8* srcS8 = (uint8*)alloc((size_t)E);
  int* esrc    = (int*)alloc((size_t)E * 4);
  int* row_ptr = (int*)alloc((size_t)(N + 1) * 4);
  float* d_src = (float*)alloc((size_t)N * 4);
  float* d_dst = (float*)alloc((size_t)N * 4);
  bf16x8* Whg  = (bf16x8*)alloc(9216 * 16);
  bf16x8* Wlg  = (bf16x8*)alloc(9216 * 16);
  unsigned short* tb0  = (unsigned short*)alloc((size_t)N * FD * 2);
  unsigned short* tb1  = (unsigned short*)alloc((size_t)N * FD * 2);
  unsigned short* resb = (unsigned short*)alloc((size_t)N * FD * 2);

  int chunk = (E + NB - 1) / NB;
  dim3 gScan(256, 2);

  k_wsplit<<<36, 256, 0, stream>>>(W1, W2, W3, Wr, Wo, Whg, Wlg);
  k_hist<<<NB, 256, 0, stream>>>(src, dst, histD, histS, E, chunk);
  k_ssum<<<gScan, 256, 0, stream>>>(histD, histS, bsums);
  k_sscan<<<1, 256, 0, stream>>>(bsums);
  k_sapply<<<gScan, 256, 0, stream>>>(histD, histS, bsums);
  k_scatter<<<NB, 256, 0, stream>>>(src, dst, histD, histS, pk, srcS8, E, chunk);
  k_bucket_dst<<<NBINS, 256, 0, stream>>>(pk, histD, esrc, row_ptr, d_dst, N, E);
  k_bucket_src<<<NBINS, 256, 0, stream>>>(srcS8, histS, d_src, N, E);

  int gG = (N + 63) / 64;
  int gA = (N + 3) / 4;

  const bf16x8* Wh1 = Whg;
  const bf16x8* Wh2 = Whg + 2048;
  const bf16x8* Wh3 = Whg + 4096;
  const bf16x8* Whr = Whg + 6144;
  const bf16x8* Who = Whg + 8192;
  const bf16x8* Wl1 = Wlg;
  const bf16x8* Wl2 = Wlg + 2048;
  const bf16x8* Wl3 = Wlg + 4096;
  const bf16x8* Wlr = Wlg + 6144;
  const bf16x8* Wlo = Wlg + 8192;

  // res = x @ Wr + br  (bf16 out)
  k_gemm<FD, false, false, true, true><<<gG, 256, 0, stream>>>(x, Whr, Wlr, br, nullptr, resb, N);
  // layer 1: h = d_src ⊙ (x @ W1)  (bf16 out)
  k_gemm<FD, false, true, false, true><<<gG, 256, 0, stream>>>(x, Wh1, Wl1, nullptr, d_src, tb0, N);
  k_agg<true, false><<<gA, 256, 0, stream>>>(tb0, row_ptr, esrc, d_dst, b1, nullptr, tb1, N);
  // layer 2
  k_gemm<FD, true, true, false, true><<<gG, 256, 0, stream>>>(tb1, Wh2, Wl2, nullptr, d_src, tb0, N);
  k_agg<true, false><<<gA, 256, 0, stream>>>(tb0, row_ptr, esrc, d_dst, b2, nullptr, tb1, N);
  // layer 3 + residual + relu
  k_gemm<FD, true, true, false, true><<<gG, 256, 0, stream>>>(tb1, Wh3, Wl3, nullptr, d_src, tb0, N);
  k_agg<true, true><<<gA, 256, 0, stream>>>(tb0, row_ptr, esrc, d_dst, b3, resb, tb1, N);
  // out = t1 @ Wo + bo  (fp32 out)
  k_gemm<CO, true, false, true, false><<<gG, 256, 0, stream>>>(tb1, Who, Wlo, bo, nullptr, out, N);
}